// Round 6
// baseline (154.862 us; speedup 1.0000x reference)
//
#include <hip/hip_runtime.h>
#include <math.h>

// DigitalGCN: B=16, N=1024, D=128, 2 iters, fp32 in/out.
// out = relu(nsadj + inv*( (G0@x) + Vtot )), nsadj = NS + b_self - inv*v,
//   x = nm*w*(NL-NR), v = nm*w*NR, inv = nm/max(nm*(S-nm),1), G0 = G diag-cleared.
// Graph packed 1 bit/edge (2 MB, byte-permuted); bits->bf16 expansion in VALU.
// Round 6: re-tiled for occupancy (latency-bound fix): prep 1024 blocks (16-row
// tiles), agg 2048 blocks (16x64 tiles, 4-way K-split). No cooperative launch.

constexpr int B = 16, N = 1024, D = 128, ITERS = 2;

typedef unsigned short u16;
typedef unsigned char u8;
typedef unsigned int u32;
typedef __attribute__((ext_vector_type(8))) short short8v;
typedef __attribute__((ext_vector_type(4))) unsigned int uint4v;
typedef __attribute__((ext_vector_type(4))) float float4v;

__device__ inline u16 f32_to_bf16(float f) {
  u32 bits = __float_as_uint(f);
  bits += 0x7FFFu + ((bits >> 16) & 1u);  // RNE
  return (u16)(bits >> 16);
}

// blocks 0..8191: pack 2 graph rows each (coalesced reads, LDS byte shuffle).
// blocks 8192..8194: W transpose to bf16. block 8195: per-batch mask sums.
__global__ __launch_bounds__(256) void pack_kernel(
    const int* __restrict__ graph, const int* __restrict__ mask,
    const float* __restrict__ w_self, const float* __restrict__ w_left,
    const float* __restrict__ w_right, u8* __restrict__ gpk, u16* __restrict__ wsT,
    u16* __restrict__ wlT, u16* __restrict__ wrT, float* __restrict__ sb) {
  int blk = blockIdx.x, tid = threadIdx.x;
  if (blk < 8192) {
    __shared__ u32 lbw[2][32];
    int rl = tid >> 7, j = tid & 127;
    int rowg = blk * 2 + rl;
    int i = rowg & (N - 1);
    const int* gp = graph + (size_t)rowg * N + j * 8;
    int4 a = *(const int4*)gp;
    int4 c = *(const int4*)(gp + 4);
    u32 by = (u32)(a.x != 0) | ((u32)(a.y != 0) << 1) | ((u32)(a.z != 0) << 2) |
             ((u32)(a.w != 0) << 3) | ((u32)(c.x != 0) << 4) |
             ((u32)(c.y != 0) << 5) | ((u32)(c.z != 0) << 6) |
             ((u32)(c.w != 0) << 7);
    if (j == (i >> 3)) by &= ~(1u << (i & 7));  // clear diagonal
    // permuted byte position: p = (j&3)*32 + (j>>2)  (A-frag fetch order)
    ((u8*)&lbw[rl][0])[(j & 3) * 32 + (j >> 2)] = (u8)by;
    __syncthreads();
    if (tid < 64) {
      int rl2 = tid >> 5, d = tid & 31;
      ((u32*)gpk)[(size_t)(blk * 2 + rl2) * 32 + d] = lbw[rl2][d];
    }
  } else if (blk < 8195) {
    __shared__ float tile[32][33];
    const float* W = (blk == 8192) ? w_self : (blk == 8193) ? w_left : w_right;
    u16* WT = (blk == 8192) ? wsT : (blk == 8193) ? wlT : wrT;
    for (int t = 0; t < 16; ++t) {
      int ti = t >> 2, tj = t & 3;
      __syncthreads();
#pragma unroll
      for (int q = 0; q < 4; ++q) {
        int idx = q * 256 + tid;
        int r = idx >> 5, cc = idx & 31;
        tile[r][cc] = W[(ti * 32 + r) * 128 + tj * 32 + cc];
      }
      __syncthreads();
#pragma unroll
      for (int q = 0; q < 4; ++q) {
        int idx = q * 256 + tid;
        int r = idx >> 5, cc = idx & 31;
        WT[(tj * 32 + r) * 128 + ti * 32 + cc] = f32_to_bf16(tile[cc][r]);
      }
    }
  } else {
    int b = tid >> 4, seg = tid & 15;
    const int* mp = mask + b * N + seg * 64;
    int s = 0;
    for (int q = 0; q < 64; ++q) s += mp[q];
    float fs = (float)s;
    fs += __shfl_xor(fs, 8, 16);
    fs += __shfl_xor(fs, 4, 16);
    fs += __shfl_xor(fs, 2, 16);
    fs += __shfl_xor(fs, 1, 16);
    if (seg == 0) sb[b] = fs;
  }
}

// prep: 16 rows/block, grid B*(N/16)=1024. 4 waves, wave w owns 32 cols (cf=2).
__global__ __launch_bounds__(256, 4) void prep_kernel(
    const float* __restrict__ node, const int* __restrict__ mask,
    const float* __restrict__ w_weight, const float* __restrict__ b_weight,
    const float* __restrict__ b_self, const u16* __restrict__ wsT,
    const u16* __restrict__ wlT, const u16* __restrict__ wrT,
    const float* __restrict__ sb, float* __restrict__ outw_t,
    float* __restrict__ nsadj, u16* __restrict__ xT, float* __restrict__ part) {
  __shared__ float nlds[16][132];
  __shared__ float wmrow[16];
  __shared__ float invrow[16];
  int tid = threadIdx.x;
  int b = blockIdx.x >> 6;
  int rt = blockIdx.x & 63;
  int r0 = rt * 16;

  const float* nbase = node + ((size_t)b * N + r0) * D;
#pragma unroll
  for (int p = 0; p < 2; ++p) {
    int g = p * 256 + tid;
    int row = g >> 5, c4 = g & 31;
    *(float4*)&nlds[row][c4 * 4] = *(const float4*)(nbase + row * 128 + c4 * 4);
  }
  __syncthreads();

  if (tid < 128) {  // node_weight: 8 threads/row, fp32
    int r = tid >> 3, jj = tid & 7;
    float acc = 0.f;
#pragma unroll
    for (int q = 0; q < 4; ++q) {
      float4 wv = *(const float4*)(w_weight + jj * 16 + q * 4);
      const float* np = &nlds[r][jj * 16 + q * 4];
      acc += np[0] * wv.x + np[1] * wv.y + np[2] * wv.z + np[3] * wv.w;
    }
    acc += __shfl_xor(acc, 4, 8);
    acc += __shfl_xor(acc, 2, 8);
    acc += __shfl_xor(acc, 1, 8);
    if (jj == 0) {
      float w = 1.f / (1.f + expf(-(acc + b_weight[0])));
      outw_t[b * (ITERS * N) + r0 + r] = w;
      float nm = (float)mask[b * N + r0 + r];
      float nnum = fmaxf(nm * (sb[b] - nm), 1.f);
      wmrow[r] = w * nm;
      invrow[r] = nm / nnum;
    }
  }
  __syncthreads();

  int w = tid >> 6, lane = tid & 63;
  int l15 = lane & 15, lg = lane >> 4;
  int ch = w * 32;

  short8v af[4];
#pragma unroll
  for (int ks = 0; ks < 4; ++ks) {
    float tmp[8];
    *(float4*)&tmp[0] = *(const float4*)&nlds[l15][ks * 32 + lg * 8];
    *(float4*)&tmp[4] = *(const float4*)&nlds[l15][ks * 32 + lg * 8 + 4];
    short8v t;
#pragma unroll
    for (int e = 0; e < 8; ++e) t[e] = (short)f32_to_bf16(tmp[e]);
    af[ks] = t;
  }

  float4v aNR[2], aNL[2], aNS[2];
#define RUN_GEMM(WT, ACC)                                                          \
  {                                                                                \
    _Pragma("unroll") for (int cf = 0; cf < 2; ++cf) {                             \
      ACC[cf] = (float4v){0.f, 0.f, 0.f, 0.f};                                     \
      const u16* bp = (WT) + (ch + cf * 16 + l15) * 128 + lg * 8;                  \
      _Pragma("unroll") for (int ks = 0; ks < 4; ++ks) {                           \
        short8v bf = *(const short8v*)(bp + ks * 32);                              \
        ACC[cf] =                                                                  \
            __builtin_amdgcn_mfma_f32_16x16x32_bf16(af[ks], bf, ACC[cf], 0, 0, 0); \
      }                                                                            \
    }                                                                              \
  }
  RUN_GEMM(wrT, aNR);
  RUN_GEMM(wlT, aNL);
  RUN_GEMM(wsT, aNS);
#undef RUN_GEMM

  float wmv[4], invv[4];
#pragma unroll
  for (int j = 0; j < 4; ++j) {
    int rloc = lg * 4 + j;
    wmv[j] = wmrow[rloc];
    invv[j] = invrow[rloc];
  }
  float pv[2] = {0.f, 0.f};
#pragma unroll
  for (int cf = 0; cf < 2; ++cf) {
    int col = ch + cf * 16 + l15;
    float bsv = b_self[col];
    u16 xb[4];
#pragma unroll
    for (int j = 0; j < 4; ++j) {
      float x = wmv[j] * (aNL[cf][j] - aNR[cf][j]);
      float v = wmv[j] * aNR[cf][j];
      pv[cf] += v;
      nsadj[((size_t)b * N + r0 + lg * 4 + j) * D + col] =
          aNS[cf][j] + bsv - invv[j] * v;
      xb[j] = f32_to_bf16(x);
    }
    *(ushort4*)&xT[((size_t)b * D + col) * N + r0 + lg * 4] = *(ushort4*)&xb[0];
  }
  // reduce v over the 4 row-groups (lanes differing in lg bits 4..5)
#pragma unroll
  for (int cf = 0; cf < 2; ++cf) {
    pv[cf] += __shfl_xor(pv[cf], 16);
    pv[cf] += __shfl_xor(pv[cf], 32);
  }
  if (lg == 0) {
#pragma unroll
    for (int cf = 0; cf < 2; ++cf)
      part[((size_t)b * 64 + rt) * 128 + ch + cf * 16 + l15] = pv[cf];
  }
}

// agg: 16 rows x 64 cols per block, grid B*(N/16)*(D/64) = 2048.
// 4 waves = K-quarters; bits->bf16 VALU expansion; LDS combine; fused epilogue.
__global__ __launch_bounds__(256, 4) void agg_kernel(
    const u8* __restrict__ gpk, const u16* __restrict__ xT,
    const int* __restrict__ mask, const float* __restrict__ nsadj,
    const float* __restrict__ part, const float* __restrict__ sb,
    float* __restrict__ out) {
  __shared__ float red[4][64];         // Vtot partial re-reduction
  __shared__ float accbuf[3][16][64];  // K-quarters 1..3
  int tid = threadIdx.x;
  int b = blockIdx.x >> 7;
  int rem = blockIdx.x & 127;
  int rt = rem >> 1, half = rem & 1;
  int r0 = rt * 16, c0 = half * 64;

  {  // Vtot: sum 64 row-tile partials for this block's 64 cols
    int col = tid & 63, grp = tid >> 6;
    float ps = 0.f;
#pragma unroll
    for (int p = 0; p < 16; ++p)
      ps += part[((size_t)b * 64 + grp * 16 + p) * 128 + c0 + col];
    red[grp][col] = ps;
  }

  int w = tid >> 6, lane = tid & 63;
  int l15 = lane & 15, lg = lane >> 4;
  int ks = w;  // K-quarter
  int arow = r0 + l15;
  const u8* gr = gpk + ((size_t)b * N + arow) * 128 + lg * 32 + ks * 8;
  uint2 q = *(const uint2*)gr;
  u32 qa[2] = {q.x, q.y};

  const u16* bp[4];
#pragma unroll
  for (int cf = 0; cf < 4; ++cf)
    bp[cf] = xT + ((size_t)b * D + c0 + cf * 16 + l15) * N + ks * 256 + lg * 8;

  float4v acc[4] = {{0.f, 0.f, 0.f, 0.f},
                    {0.f, 0.f, 0.f, 0.f},
                    {0.f, 0.f, 0.f, 0.f},
                    {0.f, 0.f, 0.f, 0.f}};
#pragma unroll
  for (int cl = 0; cl < 8; ++cl) {
    u32 by = (qa[cl >> 2] >> ((cl & 3) * 8)) & 255u;
    u32 e0 = ((by & 1u) ? 0x3F80u : 0u) | ((by & 2u) ? 0x3F800000u : 0u);
    u32 e1 = ((by & 4u) ? 0x3F80u : 0u) | ((by & 8u) ? 0x3F800000u : 0u);
    u32 e2 = ((by & 16u) ? 0x3F80u : 0u) | ((by & 32u) ? 0x3F800000u : 0u);
    u32 e3 = ((by & 64u) ? 0x3F80u : 0u) | ((by & 128u) ? 0x3F800000u : 0u);
    uint4v ev = {e0, e1, e2, e3};
    short8v a = __builtin_bit_cast(short8v, ev);
    int koff = cl * 32;
#pragma unroll
    for (int cf = 0; cf < 4; ++cf) {
      short8v bf = *(const short8v*)(bp[cf] + koff);
      acc[cf] = __builtin_amdgcn_mfma_f32_16x16x32_bf16(a, bf, acc[cf], 0, 0, 0);
    }
  }

  if (ks != 0) {
#pragma unroll
    for (int cf = 0; cf < 4; ++cf)
#pragma unroll
      for (int j = 0; j < 4; ++j)
        accbuf[ks - 1][lg * 4 + j][cf * 16 + l15] = acc[cf][j];
  }
  __syncthreads();
  if (ks == 0) {
    float sbv = sb[b];
#pragma unroll
    for (int j = 0; j < 4; ++j) {
      int orow = r0 + lg * 4 + j;
      float nm = (float)mask[b * N + orow];
      float nnum = fmaxf(nm * (sbv - nm), 1.f);
      float inv = nm / nnum;
      size_t rowoff = ((size_t)b * N + orow) * D;
#pragma unroll
      for (int cf = 0; cf < 4; ++cf) {
        int c = cf * 16 + l15;
        float vt = red[0][c] + red[1][c] + red[2][c] + red[3][c];
        float m = acc[cf][j] + accbuf[0][lg * 4 + j][c] + accbuf[1][lg * 4 + j][c] +
                  accbuf[2][lg * 4 + j][c] + vt;
        int col = c0 + c;
        out[rowoff + col] = fmaxf(nsadj[rowoff + col] + inv * m, 0.f);
      }
    }
  }
}

extern "C" void kernel_launch(void* const* d_in, const int* in_sizes, int n_in,
                              void* d_out, int out_size, void* d_ws, size_t ws_size,
                              hipStream_t stream) {
  const float* node0 = (const float*)d_in[0];
  const int* mask = (const int*)d_in[1];
  const int* graph = (const int*)d_in[2];
  const float* w_weight = (const float*)d_in[3];
  const float* b_weight = (const float*)d_in[4];
  const float* w_self = (const float*)d_in[5];
  const float* b_self = (const float*)d_in[6];
  const float* w_left = (const float*)d_in[7];
  const float* w_right = (const float*)d_in[8];
  float* out = (float*)d_out;
  float* outw = out + (size_t)B * N * D;  // all_node_weight [B,2,N]

  char* ws = (char*)d_ws;
  float* nsadj = (float*)ws;                         // 8 MB
  u16* xT = (u16*)(ws + (size_t)8 * 1024 * 1024);    // 4 MB
  u8* gpk = (u8*)(ws + (size_t)12 * 1024 * 1024);    // 2 MB
  u16* wsT = (u16*)(ws + (size_t)14 * 1024 * 1024);  // 3 x 32 KB
  u16* wlT = wsT + 16384;
  u16* wrT = wlT + 16384;
  float* part = (float*)(ws + (size_t)14 * 1024 * 1024 + 3 * 32768);  // 512 KB
  float* sb = part + (size_t)B * 64 * 128;

  pack_kernel<<<8196, 256, 0, stream>>>(graph, mask, w_self, w_left, w_right, gpk,
                                        wsT, wlT, wrT, sb);
  const float* cur = node0;
  for (int t = 0; t < ITERS; ++t) {
    prep_kernel<<<1024, 256, 0, stream>>>(cur, mask, w_weight, b_weight, b_self,
                                          wsT, wlT, wrT, sb, outw + t * N, nsadj,
                                          xT, part);
    agg_kernel<<<2048, 256, 0, stream>>>(gpk, xT, mask, nsadj, part, sb, out);
    cur = out;
  }
}

// Round 7
// 82.751 us; speedup vs baseline: 1.8714x; 1.8714x over previous
//
#include <hip/hip_runtime.h>
#include <math.h>

// DigitalGCN: B=16, N=1024, D=128, 2 iters, fp32 in/out.
// out = relu(nsadj + inv*( (G0@x) + Vtot )), nsadj = NS + b_self - inv*v,
//   x = nm*w*(NL-NR), v = nm*w*NR, inv = nm/max(nm*(S-nm),1), G0 = G diag-cleared.
// Round 7: fragment-major layouts. xF[b][cblk][kch][lane][8] / wF[cblk][ks][lane][8]
// make every MFMA B-fragment load base+lane*16B (coalesced 1KB) — fixes the
// 64-lines-per-load TA bottleneck that left round-6 agg 90% idle.

constexpr int B = 16, N = 1024, D = 128, ITERS = 2;

typedef unsigned short u16;
typedef unsigned char u8;
typedef unsigned int u32;
typedef __attribute__((ext_vector_type(8))) short short8v;
typedef __attribute__((ext_vector_type(4))) unsigned int uint4v;
typedef __attribute__((ext_vector_type(4))) float float4v;

__device__ inline u16 f32_to_bf16(float f) {
  u32 bits = __float_as_uint(f);
  bits += 0x7FFFu + ((bits >> 16) & 1u);  // RNE
  return (u16)(bits >> 16);
}

// blocks 0..8191: pack 2 graph rows each (coalesced reads, LDS byte shuffle).
// blocks 8192..8194: W -> bf16 fragment-major wF. block 8195: mask sums.
__global__ __launch_bounds__(256) void pack_kernel(
    const int* __restrict__ graph, const int* __restrict__ mask,
    const float* __restrict__ w_self, const float* __restrict__ w_left,
    const float* __restrict__ w_right, u8* __restrict__ gpk, u16* __restrict__ wsF,
    u16* __restrict__ wlF, u16* __restrict__ wrF, float* __restrict__ sb) {
  int blk = blockIdx.x, tid = threadIdx.x;
  if (blk < 8192) {
    __shared__ u32 lbw[2][32];
    int rl = tid >> 7, j = tid & 127;
    int rowg = blk * 2 + rl;
    int i = rowg & (N - 1);
    const int* gp = graph + (size_t)rowg * N + j * 8;
    int4 a = *(const int4*)gp;
    int4 c = *(const int4*)(gp + 4);
    u32 by = (u32)(a.x != 0) | ((u32)(a.y != 0) << 1) | ((u32)(a.z != 0) << 2) |
             ((u32)(a.w != 0) << 3) | ((u32)(c.x != 0) << 4) |
             ((u32)(c.y != 0) << 5) | ((u32)(c.z != 0) << 6) |
             ((u32)(c.w != 0) << 7);
    if (j == (i >> 3)) by &= ~(1u << (i & 7));  // clear diagonal
    // permuted byte position p = (j&3)*32 + (j>>2): A-frag (lane lg, kchunk) fetch
    ((u8*)&lbw[rl][0])[(j & 3) * 32 + (j >> 2)] = (u8)by;
    __syncthreads();
    if (tid < 64) {
      int rl2 = tid >> 5, d = tid & 31;
      ((u32*)gpk)[(size_t)(blk * 2 + rl2) * 32 + d] = lbw[rl2][d];
    }
  } else if (blk < 8195) {
    const float* W = (blk == 8192) ? w_self : (blk == 8193) ? w_left : w_right;
    u16* WF = (blk == 8192) ? wsF : (blk == 8193) ? wlF : wrF;
    for (int e64 = 0; e64 < 64; ++e64) {
      int o = e64 * 256 + tid;  // o = c*128 + k
      int c = o >> 7, k = o & 127;
      int cblk = c >> 4, ks = k >> 5;
      int lane = ((k >> 3) & 3) * 16 + (c & 15);
      int e = k & 7;
      WF[(((cblk * 4 + ks) * 64 + lane) << 3) + e] = f32_to_bf16(W[k * 128 + c]);
    }
  } else {
    int b = tid >> 4, seg = tid & 15;
    const int* mp = mask + b * N + seg * 64;
    int s = 0;
    for (int q = 0; q < 64; ++q) s += mp[q];
    float fs = (float)s;
    fs += __shfl_xor(fs, 8, 16);
    fs += __shfl_xor(fs, 4, 16);
    fs += __shfl_xor(fs, 2, 16);
    fs += __shfl_xor(fs, 1, 16);
    if (seg == 0) sb[b] = fs;
  }
}

// prep: 16 rows/block, grid B*(N/16)=1024. 4 waves, wave w owns 32 cols (cf=2).
// W fragments loaded coalesced from wF; x written fragment-major to xF.
__global__ __launch_bounds__(256, 4) void prep_kernel(
    const float* __restrict__ node, const int* __restrict__ mask,
    const float* __restrict__ w_weight, const float* __restrict__ b_weight,
    const float* __restrict__ b_self, const u16* __restrict__ wsF,
    const u16* __restrict__ wlF, const u16* __restrict__ wrF,
    const float* __restrict__ sb, float* __restrict__ outw_t,
    float* __restrict__ nsadj, u16* __restrict__ xF, float* __restrict__ part) {
  __shared__ float nlds[16][132];
  __shared__ float wmrow[16];
  __shared__ float invrow[16];
  int tid = threadIdx.x;
  int b = blockIdx.x >> 6;
  int rt = blockIdx.x & 63;
  int r0 = rt * 16;

  const float* nbase = node + ((size_t)b * N + r0) * D;
#pragma unroll
  for (int p = 0; p < 2; ++p) {
    int g = p * 256 + tid;
    int row = g >> 5, c4 = g & 31;
    *(float4*)&nlds[row][c4 * 4] = *(const float4*)(nbase + row * 128 + c4 * 4);
  }
  __syncthreads();

  if (tid < 128) {  // node_weight: 8 threads/row, fp32
    int r = tid >> 3, jj = tid & 7;
    float acc = 0.f;
#pragma unroll
    for (int q = 0; q < 4; ++q) {
      float4 wv = *(const float4*)(w_weight + jj * 16 + q * 4);
      const float* np = &nlds[r][jj * 16 + q * 4];
      acc += np[0] * wv.x + np[1] * wv.y + np[2] * wv.z + np[3] * wv.w;
    }
    acc += __shfl_xor(acc, 4, 8);
    acc += __shfl_xor(acc, 2, 8);
    acc += __shfl_xor(acc, 1, 8);
    if (jj == 0) {
      float w = 1.f / (1.f + expf(-(acc + b_weight[0])));
      outw_t[b * (ITERS * N) + r0 + r] = w;
      float nm = (float)mask[b * N + r0 + r];
      float nnum = fmaxf(nm * (sb[b] - nm), 1.f);
      wmrow[r] = w * nm;
      invrow[r] = nm / nnum;
    }
  }
  __syncthreads();

  int w = tid >> 6, lane = tid & 63;
  int l15 = lane & 15, lg = lane >> 4;
  int ch = w * 32;

  short8v af[4];
#pragma unroll
  for (int ks = 0; ks < 4; ++ks) {
    float tmp[8];
    *(float4*)&tmp[0] = *(const float4*)&nlds[l15][ks * 32 + lg * 8];
    *(float4*)&tmp[4] = *(const float4*)&nlds[l15][ks * 32 + lg * 8 + 4];
    short8v t;
#pragma unroll
    for (int e = 0; e < 8; ++e) t[e] = (short)f32_to_bf16(tmp[e]);
    af[ks] = t;
  }

  float4v aNR[2], aNL[2], aNS[2];
#define RUN_GEMM(WF, ACC)                                                          \
  {                                                                                \
    _Pragma("unroll") for (int cf = 0; cf < 2; ++cf) {                             \
      ACC[cf] = (float4v){0.f, 0.f, 0.f, 0.f};                                     \
      int cblk = w * 2 + cf;                                                       \
      const u16* bp = (WF) + (((cblk * 4) * 64 + lane) << 3);                      \
      _Pragma("unroll") for (int ks = 0; ks < 4; ++ks) {                           \
        short8v bf = *(const short8v*)(bp + ks * 512);                             \
        ACC[cf] =                                                                  \
            __builtin_amdgcn_mfma_f32_16x16x32_bf16(af[ks], bf, ACC[cf], 0, 0, 0); \
      }                                                                            \
    }                                                                              \
  }
  RUN_GEMM(wrF, aNR);
  RUN_GEMM(wlF, aNL);
  RUN_GEMM(wsF, aNS);
#undef RUN_GEMM

  float wmv[4], invv[4];
#pragma unroll
  for (int j = 0; j < 4; ++j) {
    int rloc = lg * 4 + j;
    wmv[j] = wmrow[rloc];
    invv[j] = invrow[rloc];
  }
  int kch = rt >> 1;                              // this block's rows = k-chunk
  int lane_f = ((rt & 1) * 2 + (lg >> 1)) * 16;   // + (c&15)
  int e0 = (lg & 1) * 4;
  float pv[2] = {0.f, 0.f};
#pragma unroll
  for (int cf = 0; cf < 2; ++cf) {
    int col = ch + cf * 16 + l15;
    float bsv = b_self[col];
    u16 xb[4];
#pragma unroll
    for (int j = 0; j < 4; ++j) {
      float x = wmv[j] * (aNL[cf][j] - aNR[cf][j]);
      float v = wmv[j] * aNR[cf][j];
      pv[cf] += v;
      nsadj[((size_t)b * N + r0 + lg * 4 + j) * D + col] =
          aNS[cf][j] + bsv - invv[j] * v;
      xb[j] = f32_to_bf16(x);
    }
    int cblk = w * 2 + cf;
    size_t fi = ((((size_t)b * 8 + cblk) * 32 + kch) * 64 + lane_f + l15) * 8 + e0;
    *(ushort4*)&xF[fi] = *(ushort4*)&xb[0];
  }
#pragma unroll
  for (int cf = 0; cf < 2; ++cf) {
    pv[cf] += __shfl_xor(pv[cf], 16);
    pv[cf] += __shfl_xor(pv[cf], 32);
  }
  if (lg == 0) {
#pragma unroll
    for (int cf = 0; cf < 2; ++cf)
      part[((size_t)b * 64 + rt) * 128 + ch + cf * 16 + l15] = pv[cf];
  }
}

// agg: 32 rows x 64 cols per block, grid B*(N/32)*(D/64) = 1024 (4 blocks/CU).
// 4 waves = K-quarters (256 k each); acc 2 rf x 4 cf; coalesced xF loads.
__global__ __launch_bounds__(256, 4) void agg_kernel(
    const u8* __restrict__ gpk, const u16* __restrict__ xF,
    const int* __restrict__ mask, const float* __restrict__ nsadj,
    const float* __restrict__ part, const float* __restrict__ sb,
    float* __restrict__ out) {
  __shared__ float red[4][64];         // Vtot partial re-reduction
  __shared__ float accbuf[3][32][68];  // K-quarters 1..3, padded (+4)
  int tid = threadIdx.x;
  int b = blockIdx.x >> 6;
  int rem = blockIdx.x & 63;
  int rt = rem >> 1, half = rem & 1;
  int r0 = rt * 32, c0 = half * 64;

  {  // Vtot partials: 64 consecutive floats per load (coalesced)
    int col = tid & 63, grp = tid >> 6;
    float ps = 0.f;
#pragma unroll
    for (int p = 0; p < 16; ++p)
      ps += part[((size_t)b * 64 + grp * 16 + p) * 128 + c0 + col];
    red[grp][col] = ps;
  }

  int w = tid >> 6, lane = tid & 63;
  int l15 = lane & 15, lg = lane >> 4;
  int ks = w;  // K-quarter: kchunks [ks*8, ks*8+8)
  u32 qa[2][2];
#pragma unroll
  for (int rf = 0; rf < 2; ++rf) {
    const u8* gr =
        gpk + ((size_t)b * N + r0 + rf * 16 + l15) * 128 + lg * 32 + ks * 8;
    uint2 q = *(const uint2*)gr;
    qa[rf][0] = q.x;
    qa[rf][1] = q.y;
  }

  const u16* bp[4];
#pragma unroll
  for (int cf = 0; cf < 4; ++cf) {
    int cblk = half * 4 + cf;
    bp[cf] = xF + ((((size_t)b * 8 + cblk) * 32 + ks * 8) * 64 + lane) * 8;
  }

  float4v acc[2][4] = {{{0.f, 0.f, 0.f, 0.f}, {0.f, 0.f, 0.f, 0.f},
                        {0.f, 0.f, 0.f, 0.f}, {0.f, 0.f, 0.f, 0.f}},
                       {{0.f, 0.f, 0.f, 0.f}, {0.f, 0.f, 0.f, 0.f},
                        {0.f, 0.f, 0.f, 0.f}, {0.f, 0.f, 0.f, 0.f}}};
#pragma unroll
  for (int cl = 0; cl < 8; ++cl) {
    short8v a[2];
#pragma unroll
    for (int rf = 0; rf < 2; ++rf) {
      u32 by = (qa[rf][cl >> 2] >> ((cl & 3) * 8)) & 255u;
      u32 e0 = ((by & 1u) ? 0x3F80u : 0u) | ((by & 2u) ? 0x3F800000u : 0u);
      u32 e1 = ((by & 4u) ? 0x3F80u : 0u) | ((by & 8u) ? 0x3F800000u : 0u);
      u32 e2 = ((by & 16u) ? 0x3F80u : 0u) | ((by & 32u) ? 0x3F800000u : 0u);
      u32 e3 = ((by & 64u) ? 0x3F80u : 0u) | ((by & 128u) ? 0x3F800000u : 0u);
      uint4v ev = {e0, e1, e2, e3};
      a[rf] = __builtin_bit_cast(short8v, ev);
    }
    int koff = cl * 512;  // next kchunk: 64 lanes * 8 elems
#pragma unroll
    for (int cf = 0; cf < 4; ++cf) {
      short8v bf = *(const short8v*)(bp[cf] + koff);
#pragma unroll
      for (int rf = 0; rf < 2; ++rf)
        acc[rf][cf] =
            __builtin_amdgcn_mfma_f32_16x16x32_bf16(a[rf], bf, acc[rf][cf], 0, 0, 0);
    }
  }

  if (ks != 0) {
#pragma unroll
    for (int rf = 0; rf < 2; ++rf)
#pragma unroll
      for (int cf = 0; cf < 4; ++cf)
#pragma unroll
        for (int j = 0; j < 4; ++j)
          accbuf[ks - 1][rf * 16 + lg * 4 + j][cf * 16 + l15] = acc[rf][cf][j];
  }
  __syncthreads();
  if (ks == 0) {
    float sbv = sb[b];
#pragma unroll
    for (int rf = 0; rf < 2; ++rf) {
#pragma unroll
      for (int j = 0; j < 4; ++j) {
        int rloc = rf * 16 + lg * 4 + j;
        int orow = r0 + rloc;
        float nm = (float)mask[b * N + orow];
        float nnum = fmaxf(nm * (sbv - nm), 1.f);
        float inv = nm / nnum;
        size_t rowoff = ((size_t)b * N + orow) * D;
#pragma unroll
        for (int cf = 0; cf < 4; ++cf) {
          int c = cf * 16 + l15;
          float vt = red[0][c] + red[1][c] + red[2][c] + red[3][c];
          float m = acc[rf][cf][j] + accbuf[0][rloc][c] + accbuf[1][rloc][c] +
                    accbuf[2][rloc][c] + vt;
          int col = c0 + c;
          out[rowoff + col] = fmaxf(nsadj[rowoff + col] + inv * m, 0.f);
        }
      }
    }
  }
}

extern "C" void kernel_launch(void* const* d_in, const int* in_sizes, int n_in,
                              void* d_out, int out_size, void* d_ws, size_t ws_size,
                              hipStream_t stream) {
  const float* node0 = (const float*)d_in[0];
  const int* mask = (const int*)d_in[1];
  const int* graph = (const int*)d_in[2];
  const float* w_weight = (const float*)d_in[3];
  const float* b_weight = (const float*)d_in[4];
  const float* w_self = (const float*)d_in[5];
  const float* b_self = (const float*)d_in[6];
  const float* w_left = (const float*)d_in[7];
  const float* w_right = (const float*)d_in[8];
  float* out = (float*)d_out;
  float* outw = out + (size_t)B * N * D;  // all_node_weight [B,2,N]

  char* ws = (char*)d_ws;
  float* nsadj = (float*)ws;                         // 8 MB
  u16* xF = (u16*)(ws + (size_t)8 * 1024 * 1024);    // 4 MB (frag-major)
  u8* gpk = (u8*)(ws + (size_t)12 * 1024 * 1024);    // 2 MB
  u16* wsF = (u16*)(ws + (size_t)14 * 1024 * 1024);  // 3 x 32 KB (frag-major)
  u16* wlF = wsF + 16384;
  u16* wrF = wlF + 16384;
  float* part = (float*)(ws + (size_t)14 * 1024 * 1024 + 3 * 32768);  // 512 KB
  float* sb = part + (size_t)B * 64 * 128;

  pack_kernel<<<8196, 256, 0, stream>>>(graph, mask, w_self, w_left, w_right, gpk,
                                        wsF, wlF, wrF, sb);
  const float* cur = node0;
  for (int t = 0; t < ITERS; ++t) {
    prep_kernel<<<1024, 256, 0, stream>>>(cur, mask, w_weight, b_weight, b_self,
                                          wsF, wlF, wrF, sb, outw + t * N, nsadj,
                                          xF, part);
    agg_kernel<<<1024, 256, 0, stream>>>(gpk, xF, mask, nsadj, part, sb, out);
    cur = out;
  }
}

// Round 8
// 71.275 us; speedup vs baseline: 2.1727x; 1.1610x over previous
//
#include <hip/hip_runtime.h>
#include <math.h>

// DigitalGCN: B=16, N=1024, D=128, 2 iters, fp32 in/out.
// out = relu(nsadj + inv*( (G0@x) + Vtot )), nsadj = NS + b_self - inv*v,
//   x = nm*w*(NL-NR), v = nm*w*NR, inv = nm/max(nm*(S-nm),1), G0 = G diag-cleared.
// Round 8: pipeline fusion. 4 dispatches:
//   wpack (W->frag tables + mask sums)
//   prep_pack (graph bit-pack fused with prep t=0)        -> gpk, A-buffers
//   agg_prep (agg t=0, 16x128 tile, + prep t=1 from LDS)  -> B-buffers (no out0!)
//   agg_fin  (agg t=1 -> final out)
// Inner loops identical to the verified round-7 kernels.

constexpr int B = 16, N = 1024, D = 128, ITERS = 2;

typedef unsigned short u16;
typedef unsigned char u8;
typedef unsigned int u32;
typedef __attribute__((ext_vector_type(8))) short short8v;
typedef __attribute__((ext_vector_type(4))) unsigned int uint4v;
typedef __attribute__((ext_vector_type(4))) float float4v;

__device__ inline u16 f32_to_bf16(float f) {
  u32 bits = __float_as_uint(f);
  bits += 0x7FFFu + ((bits >> 16) & 1u);  // RNE
  return (u16)(bits >> 16);
}

// blocks 0..11: W fragment tables (output-major, coalesced writes).
// block 12: per-batch mask sums.
__global__ __launch_bounds__(256) void wpack_kernel(
    const float* __restrict__ w_self, const float* __restrict__ w_left,
    const float* __restrict__ w_right, const int* __restrict__ mask,
    u16* __restrict__ wsF, u16* __restrict__ wlF, u16* __restrict__ wrF,
    float* __restrict__ sb) {
  int blk = blockIdx.x, tid = threadIdx.x;
  if (blk < 12) {
    int widx = blk >> 2, seg = blk & 3;
    const float* W = (widx == 0) ? w_self : (widx == 1) ? w_left : w_right;
    u16* WF = (widx == 0) ? wsF : (widx == 1) ? wlF : wrF;
#pragma unroll
    for (int q = 0; q < 16; ++q) {
      int o = seg * 4096 + q * 256 + tid;  // frag-major output index
      int e = o & 7, lane = (o >> 3) & 63, ks = (o >> 9) & 3, cblk = o >> 11;
      int c = cblk * 16 + (lane & 15);
      int k = ks * 32 + ((lane >> 4) & 3) * 8 + e;
      WF[o] = f32_to_bf16(W[k * 128 + c]);
    }
  } else {
    int b = tid >> 4, seg = tid & 15;
    const int* mp = mask + b * N + seg * 64;
    int s = 0;
    for (int q = 0; q < 64; ++q) s += mp[q];
    float fs = (float)s;
    fs += __shfl_xor(fs, 8, 16);
    fs += __shfl_xor(fs, 4, 16);
    fs += __shfl_xor(fs, 2, 16);
    fs += __shfl_xor(fs, 1, 16);
    if (seg == 0) sb[b] = fs;
  }
}

// prep body (round-7 verified): nlds[16][132] holds the 16 node rows; emits
// node_weight (outw), nsadj, fragment-major xF, per-tile v partials.
__device__ __forceinline__ void prep_body(
    float (*nlds)[132], float* wmrow, float* invrow, int b, int rt, int tid,
    const int* __restrict__ mask, const float* __restrict__ w_weight,
    const float* __restrict__ b_weight, const float* __restrict__ b_self,
    const u16* __restrict__ wsF, const u16* __restrict__ wlF,
    const u16* __restrict__ wrF, const float* __restrict__ sb,
    float* __restrict__ outw_t, float* __restrict__ nsadj, u16* __restrict__ xF,
    float* __restrict__ part) {
  int r0 = rt * 16;
  if (tid < 128) {  // node_weight: 8 threads/row, fp32
    int r = tid >> 3, jj = tid & 7;
    float acc = 0.f;
#pragma unroll
    for (int q = 0; q < 4; ++q) {
      float4 wv = *(const float4*)(w_weight + jj * 16 + q * 4);
      const float* np = &nlds[r][jj * 16 + q * 4];
      acc += np[0] * wv.x + np[1] * wv.y + np[2] * wv.z + np[3] * wv.w;
    }
    acc += __shfl_xor(acc, 4, 8);
    acc += __shfl_xor(acc, 2, 8);
    acc += __shfl_xor(acc, 1, 8);
    if (jj == 0) {
      float w = 1.f / (1.f + expf(-(acc + b_weight[0])));
      outw_t[b * (ITERS * N) + r0 + r] = w;
      float nm = (float)mask[b * N + r0 + r];
      float nnum = fmaxf(nm * (sb[b] - nm), 1.f);
      wmrow[r] = w * nm;
      invrow[r] = nm / nnum;
    }
  }
  __syncthreads();

  int w = tid >> 6, lane = tid & 63;
  int l15 = lane & 15, lg = lane >> 4;
  int ch = w * 32;

  short8v af[4];
#pragma unroll
  for (int ks = 0; ks < 4; ++ks) {
    float tmp[8];
    *(float4*)&tmp[0] = *(const float4*)&nlds[l15][ks * 32 + lg * 8];
    *(float4*)&tmp[4] = *(const float4*)&nlds[l15][ks * 32 + lg * 8 + 4];
    short8v t;
#pragma unroll
    for (int e = 0; e < 8; ++e) t[e] = (short)f32_to_bf16(tmp[e]);
    af[ks] = t;
  }

  float4v aNR[2], aNL[2], aNS[2];
#define RUN_GEMM(WF, ACC)                                                          \
  {                                                                                \
    _Pragma("unroll") for (int cf = 0; cf < 2; ++cf) {                             \
      ACC[cf] = (float4v){0.f, 0.f, 0.f, 0.f};                                     \
      int cblk = w * 2 + cf;                                                       \
      const u16* bp = (WF) + (((cblk * 4) * 64 + lane) << 3);                      \
      _Pragma("unroll") for (int ks = 0; ks < 4; ++ks) {                           \
        short8v bf = *(const short8v*)(bp + ks * 512);                             \
        ACC[cf] =                                                                  \
            __builtin_amdgcn_mfma_f32_16x16x32_bf16(af[ks], bf, ACC[cf], 0, 0, 0); \
      }                                                                            \
    }                                                                              \
  }
  RUN_GEMM(wrF, aNR);
  RUN_GEMM(wlF, aNL);
  RUN_GEMM(wsF, aNS);
#undef RUN_GEMM

  float wmv[4], invv[4];
#pragma unroll
  for (int j = 0; j < 4; ++j) {
    int rloc = lg * 4 + j;
    wmv[j] = wmrow[rloc];
    invv[j] = invrow[rloc];
  }
  int kch = rt >> 1;
  int lane_f = ((rt & 1) * 2 + (lg >> 1)) * 16;
  int e0 = (lg & 1) * 4;
  float pv[2] = {0.f, 0.f};
#pragma unroll
  for (int cf = 0; cf < 2; ++cf) {
    int col = ch + cf * 16 + l15;
    float bsv = b_self[col];
    u16 xb[4];
#pragma unroll
    for (int j = 0; j < 4; ++j) {
      float x = wmv[j] * (aNL[cf][j] - aNR[cf][j]);
      float v = wmv[j] * aNR[cf][j];
      pv[cf] += v;
      nsadj[((size_t)b * N + r0 + lg * 4 + j) * D + col] =
          aNS[cf][j] + bsv - invv[j] * v;
      xb[j] = f32_to_bf16(x);
    }
    int cblk = w * 2 + cf;
    size_t fi = ((((size_t)b * 8 + cblk) * 32 + kch) * 64 + lane_f + l15) * 8 + e0;
    *(ushort4*)&xF[fi] = *(ushort4*)&xb[0];
  }
#pragma unroll
  for (int cf = 0; cf < 2; ++cf) {
    pv[cf] += __shfl_xor(pv[cf], 16);
    pv[cf] += __shfl_xor(pv[cf], 32);
  }
  if (lg == 0) {
#pragma unroll
    for (int cf = 0; cf < 2; ++cf)
      part[((size_t)b * 64 + rt) * 128 + ch + cf * 16 + l15] = pv[cf];
  }
}

// agg tile (16 rows x 128 cols): 4 waves = K-quarters, accbuf[4] combine,
// epilogue distributed (wave w -> rows [4w,4w+4)). Returns relu'd values:
// ov[e] for row = 4*(tid>>6) + ((tid&63)>>4), col = (tid&15)*8 + e.
__device__ __forceinline__ void agg_tile(
    const u8* __restrict__ gpk, const u16* __restrict__ xF,
    const float* __restrict__ part, const float* __restrict__ sb,
    const int* __restrict__ mask, const float* __restrict__ nsadj, int b, int r0,
    int tid, float (*accbuf)[16][132], float* vt_s, float ov[8]) {
  if (tid < 128) {  // Vtot for this tile's 128 cols
    float s = 0.f;
#pragma unroll
    for (int p = 0; p < 64; ++p) s += part[((size_t)b * 64 + p) * 128 + tid];
    vt_s[tid] = s;
  }
  int w = tid >> 6, lane = tid & 63;
  int l15 = lane & 15, lg = lane >> 4;
  int ks = w;  // K-quarter: kchunks [ks*8, ks*8+8)
  const u8* gr = gpk + ((size_t)b * N + r0 + l15) * 128 + lg * 32 + ks * 8;
  uint2 q = *(const uint2*)gr;
  u32 qa[2] = {q.x, q.y};

  const u16* bp[8];
#pragma unroll
  for (int cf = 0; cf < 8; ++cf)
    bp[cf] = xF + ((((size_t)b * 8 + cf) * 32 + ks * 8) * 64 + lane) * 8;

  float4v acc[8] = {{0.f, 0.f, 0.f, 0.f}, {0.f, 0.f, 0.f, 0.f},
                    {0.f, 0.f, 0.f, 0.f}, {0.f, 0.f, 0.f, 0.f},
                    {0.f, 0.f, 0.f, 0.f}, {0.f, 0.f, 0.f, 0.f},
                    {0.f, 0.f, 0.f, 0.f}, {0.f, 0.f, 0.f, 0.f}};
#pragma unroll
  for (int cl = 0; cl < 8; ++cl) {
    u32 by = (qa[cl >> 2] >> ((cl & 3) * 8)) & 255u;
    u32 e0 = ((by & 1u) ? 0x3F80u : 0u) | ((by & 2u) ? 0x3F800000u : 0u);
    u32 e1 = ((by & 4u) ? 0x3F80u : 0u) | ((by & 8u) ? 0x3F800000u : 0u);
    u32 e2 = ((by & 16u) ? 0x3F80u : 0u) | ((by & 32u) ? 0x3F800000u : 0u);
    u32 e3 = ((by & 64u) ? 0x3F80u : 0u) | ((by & 128u) ? 0x3F800000u : 0u);
    uint4v ev = {e0, e1, e2, e3};
    short8v a = __builtin_bit_cast(short8v, ev);
    int koff = cl * 512;
#pragma unroll
    for (int cf = 0; cf < 8; ++cf) {
      short8v bf = *(const short8v*)(bp[cf] + koff);
      acc[cf] = __builtin_amdgcn_mfma_f32_16x16x32_bf16(a, bf, acc[cf], 0, 0, 0);
    }
  }
#pragma unroll
  for (int cf = 0; cf < 8; ++cf)
#pragma unroll
    for (int j = 0; j < 4; ++j) accbuf[w][lg * 4 + j][cf * 16 + l15] = acc[cf][j];
  __syncthreads();

  int row = w * 4 + (lane >> 4);
  int colb = (tid & 15) * 8;
  int orow = r0 + row;
  float nm = (float)mask[b * N + orow];
  float sbv = sb[b];
  float nnum = fmaxf(nm * (sbv - nm), 1.f);
  float inv = nm / nnum;
  const float* nsp = nsadj + ((size_t)b * N + orow) * D + colb;
  float4 n0 = *(const float4*)nsp;
  float4 n1 = *(const float4*)(nsp + 4);
  float nsa[8] = {n0.x, n0.y, n0.z, n0.w, n1.x, n1.y, n1.z, n1.w};
#pragma unroll
  for (int e = 0; e < 8; ++e) {
    int c = colb + e;
    float m = accbuf[0][row][c] + accbuf[1][row][c] + accbuf[2][row][c] +
              accbuf[3][row][c] + vt_s[c];
    ov[e] = fmaxf(nsa[e] + inv * m, 0.f);
  }
}

// prep t=0 with fused 16-row graph bit-pack.
__global__ __launch_bounds__(256, 4) void prep_pack_kernel(
    const float* __restrict__ node, const int* __restrict__ graph,
    const int* __restrict__ mask, const float* __restrict__ w_weight,
    const float* __restrict__ b_weight, const float* __restrict__ b_self,
    const u16* __restrict__ wsF, const u16* __restrict__ wlF,
    const u16* __restrict__ wrF, const float* __restrict__ sb,
    u8* __restrict__ gpk, float* __restrict__ outw, float* __restrict__ nsadjA,
    u16* __restrict__ xFA, float* __restrict__ partA) {
  __shared__ float nlds[16][132];
  __shared__ float wmrow[16], invrow[16];
  __shared__ u32 lbw[2][32];
  int tid = threadIdx.x;
  int b = blockIdx.x >> 6;
  int rt = blockIdx.x & 63;
  int r0 = rt * 16;

  {  // pack this block's 16 graph rows (2 rows per pass, coalesced)
    int rl = tid >> 7, j = tid & 127;
#pragma unroll
    for (int pp = 0; pp < 8; ++pp) {
      int i = r0 + pp * 2 + rl;
      const int* gp = graph + ((size_t)b * N + i) * N + j * 8;
      int4 a = *(const int4*)gp;
      int4 c = *(const int4*)(gp + 4);
      u32 by = (u32)(a.x != 0) | ((u32)(a.y != 0) << 1) | ((u32)(a.z != 0) << 2) |
               ((u32)(a.w != 0) << 3) | ((u32)(c.x != 0) << 4) |
               ((u32)(c.y != 0) << 5) | ((u32)(c.z != 0) << 6) |
               ((u32)(c.w != 0) << 7);
      if (j == (i >> 3)) by &= ~(1u << (i & 7));  // clear diagonal
      ((u8*)&lbw[rl][0])[(j & 3) * 32 + (j >> 2)] = (u8)by;
      __syncthreads();
      if (tid < 64) {
        int rl2 = tid >> 5, d = tid & 31;
        ((u32*)gpk)[((size_t)b * N + r0 + pp * 2 + rl2) * 32 + d] = lbw[rl2][d];
      }
      __syncthreads();
    }
  }

  const float* nbase = node + ((size_t)b * N + r0) * D;
#pragma unroll
  for (int p = 0; p < 2; ++p) {
    int g = p * 256 + tid;
    int row = g >> 5, c4 = g & 31;
    *(float4*)&nlds[row][c4 * 4] = *(const float4*)(nbase + row * 128 + c4 * 4);
  }
  __syncthreads();

  prep_body(nlds, wmrow, invrow, b, rt, tid, mask, w_weight, b_weight, b_self, wsF,
            wlF, wrF, sb, outw, nsadjA, xFA, partA);
}

// agg t=0 (reads A buffers) fused with prep t=1 (writes B buffers). out0 stays
// in LDS only.
__global__ __launch_bounds__(256, 3) void agg_prep_kernel(
    const u8* __restrict__ gpk, const int* __restrict__ mask,
    const float* __restrict__ w_weight, const float* __restrict__ b_weight,
    const float* __restrict__ b_self, const u16* __restrict__ wsF,
    const u16* __restrict__ wlF, const u16* __restrict__ wrF,
    const float* __restrict__ sb, const float* __restrict__ nsadjA,
    const u16* __restrict__ xFA, const float* __restrict__ partA,
    float* __restrict__ outw, float* __restrict__ nsadjB, u16* __restrict__ xFB,
    float* __restrict__ partB) {
  __shared__ float accbuf[4][16][132];  // 33.8 KB
  __shared__ float vt_s[128];
  __shared__ float nlds[16][132];
  __shared__ float wmrow[16], invrow[16];
  int tid = threadIdx.x;
  int b = blockIdx.x >> 6;
  int rt = blockIdx.x & 63;
  int r0 = rt * 16;

  float ov[8];
  agg_tile(gpk, xFA, partA, sb, mask, nsadjA, b, r0, tid, accbuf, vt_s, ov);

  int row = (tid >> 6) * 4 + ((tid & 63) >> 4);
  int colb = (tid & 15) * 8;
#pragma unroll
  for (int e = 0; e < 8; ++e) nlds[row][colb + e] = ov[e];
  __syncthreads();

  prep_body(nlds, wmrow, invrow, b, rt, tid, mask, w_weight, b_weight, b_self, wsF,
            wlF, wrF, sb, outw + N /* t=1 */, nsadjB, xFB, partB);
}

// agg t=1 -> final out.
__global__ __launch_bounds__(256, 4) void agg_fin_kernel(
    const u8* __restrict__ gpk, const int* __restrict__ mask,
    const float* __restrict__ sb, const float* __restrict__ nsadjB,
    const u16* __restrict__ xFB, const float* __restrict__ partB,
    float* __restrict__ out) {
  __shared__ float accbuf[4][16][132];
  __shared__ float vt_s[128];
  int tid = threadIdx.x;
  int b = blockIdx.x >> 6;
  int rt = blockIdx.x & 63;
  int r0 = rt * 16;

  float ov[8];
  agg_tile(gpk, xFB, partB, sb, mask, nsadjB, b, r0, tid, accbuf, vt_s, ov);

  int row = (tid >> 6) * 4 + ((tid & 63) >> 4);
  int colb = (tid & 15) * 8;
  float* op = out + ((size_t)b * N + r0 + row) * D + colb;
  float4 o0 = {ov[0], ov[1], ov[2], ov[3]};
  float4 o1 = {ov[4], ov[5], ov[6], ov[7]};
  *(float4*)op = o0;
  *(float4*)(op + 4) = o1;
}

extern "C" void kernel_launch(void* const* d_in, const int* in_sizes, int n_in,
                              void* d_out, int out_size, void* d_ws, size_t ws_size,
                              hipStream_t stream) {
  const float* node0 = (const float*)d_in[0];
  const int* mask = (const int*)d_in[1];
  const int* graph = (const int*)d_in[2];
  const float* w_weight = (const float*)d_in[3];
  const float* b_weight = (const float*)d_in[4];
  const float* w_self = (const float*)d_in[5];
  const float* b_self = (const float*)d_in[6];
  const float* w_left = (const float*)d_in[7];
  const float* w_right = (const float*)d_in[8];
  float* out = (float*)d_out;
  float* outw = out + (size_t)B * N * D;  // all_node_weight [B,2,N]

  char* ws = (char*)d_ws;
  const size_t MB = 1024 * 1024;
  float* nsadjA = (float*)ws;                  // 8 MB
  float* nsadjB = (float*)(ws + 8 * MB);       // 8 MB
  u16* xFA = (u16*)(ws + 16 * MB);             // 4 MB
  u16* xFB = (u16*)(ws + 20 * MB);             // 4 MB
  u8* gpk = (u8*)(ws + 24 * MB);               // 2 MB
  u16* wsF = (u16*)(ws + 26 * MB);             // 3 x 32 KB
  u16* wlF = wsF + 16384;
  u16* wrF = wlF + 16384;
  float* partA = (float*)(ws + 26 * MB + 3 * 32768);  // 512 KB
  float* partB = partA + (size_t)B * 64 * 128;        // 512 KB
  float* sb = partB + (size_t)B * 64 * 128;

  wpack_kernel<<<13, 256, 0, stream>>>(w_self, w_left, w_right, mask, wsF, wlF,
                                       wrF, sb);
  prep_pack_kernel<<<1024, 256, 0, stream>>>(node0, graph, mask, w_weight,
                                             b_weight, b_self, wsF, wlF, wrF, sb,
                                             gpk, outw, nsadjA, xFA, partA);
  agg_prep_kernel<<<1024, 256, 0, stream>>>(gpk, mask, w_weight, b_weight, b_self,
                                            wsF, wlF, wrF, sb, nsadjA, xFA, partA,
                                            outw, nsadjB, xFB, partB);
  agg_fin_kernel<<<1024, 256, 0, stream>>>(gpk, mask, sb, nsadjB, xFB, partB, out);
}